// Round 1
// baseline (360.864 us; speedup 1.0000x reference)
//
#include <hip/hip_runtime.h>

// ---------------------------------------------------------------- constants
#define TT 2048
#define BB 8
#define CC 512
#define HH 8
#define DD 64
#define MM (TT*BB)          // 16384 GEMM rows
#define LDP 72              // padded LDS leading dim (bf16 elems): 144B stride -> 2-way max conflict
#define QSCALE (0.125f * 1.44269950408889634f)   // (1/sqrt(D)) * log2(e), folded into stored Q

// ws byte offsets
#define OFF_WQ 0u
#define OFF_WK (512u<<10)
#define OFF_WV (1024u<<10)
#define OFF_WO (1536u<<10)
#define OFF_Q  (2u<<20)      // 16 MB  [B,H,T,D] bf16 (pre-scaled by QSCALE)
#define OFF_K  (18u<<20)     // 16 MB  [B,H,T,D] bf16
#define OFF_VT (34u<<20)     // 16 MB  [B,H,D,T] bf16
#define OFF_V  (50u<<20)     // 16 MB  [B,H,T,D] bf16; dead after transpose
#define OFF_Y  OFF_V         // attention output [B,T,C] bf16 reuses V region

typedef __attribute__((ext_vector_type(8)))  unsigned short us8;
typedef __attribute__((ext_vector_type(4)))  unsigned short us4;
typedef __attribute__((ext_vector_type(4)))  float f4;
typedef __bf16 bf8v __attribute__((ext_vector_type(8)));

__device__ __forceinline__ unsigned short f2bf(float f) {
  unsigned u = __float_as_uint(f);
  u += 0x7fffu + ((u >> 16) & 1u);          // RNE
  return (unsigned short)(u >> 16);
}

__device__ __forceinline__ f4 MFMA(us8 a, us8 b, f4 c) {
  return __builtin_amdgcn_mfma_f32_16x16x32_bf16(
      __builtin_bit_cast(bf8v, a), __builtin_bit_cast(bf8v, b), c, 0, 0, 0);
}

// ---------------------------------------------------------------- prep: weights f32 -> bf16
__global__ __launch_bounds__(256) void prep_w(const float* wq, const float* wk,
                                              const float* wv, const float* wo,
                                              unsigned short* dst) {
  int i = blockIdx.x * 256 + threadIdx.x;   // 0..65535, one float4 per matrix
  const float* srcs[4] = {wq, wk, wv, wo};
#pragma unroll
  for (int m = 0; m < 4; m++) {
    f4 v = ((const f4*)srcs[m])[i];
    us4 o;
    o[0] = f2bf(v[0]); o[1] = f2bf(v[1]); o[2] = f2bf(v[2]); o[3] = f2bf(v[3]);
    ((us4*)(dst + m * 262144))[i] = o;
  }
}

// ---------------------------------------------------------------- GEMM core: C[128,128] tile of X[M,512] @ Wb[512,512]^T
// X row-major [M][512] (f32 or bf16), Wb row-major bf16 [512][512] (so both frags are k-contiguous).
template <bool XF32>
__device__ __forceinline__ void gemm_core(const void* Xv, const unsigned short* W,
                                          int m0, int n0, f4 acc[4][4],
                                          unsigned short* XsL, unsigned short* WsL) {
  const int tid = threadIdx.x;
  const int w = tid >> 6, lane = tid & 63, g = lane >> 4, l16 = lane & 15;
  const int wr = w >> 1, wc = w & 1;
#pragma unroll
  for (int m = 0; m < 4; m++)
#pragma unroll
    for (int n = 0; n < 4; n++) acc[m][n] = (f4){0.f, 0.f, 0.f, 0.f};

  for (int kk = 0; kk < CC; kk += 64) {
    __syncthreads();   // previous iteration's reads done before restage
#pragma unroll
    for (int i = 0; i < 4; i++) {            // stage X tile 128x64
      int c = tid + 256 * i;                 // chunk id, 8 elems each
      int r = c >> 3, k8 = c & 7;
      if (XF32) {
        const float* src = (const float*)Xv + (size_t)(m0 + r) * CC + kk + k8 * 8;
        f4 v0 = ((const f4*)src)[0];
        f4 v1 = ((const f4*)src)[1];
        us8 o;
        o[0] = f2bf(v0[0]); o[1] = f2bf(v0[1]); o[2] = f2bf(v0[2]); o[3] = f2bf(v0[3]);
        o[4] = f2bf(v1[0]); o[5] = f2bf(v1[1]); o[6] = f2bf(v1[2]); o[7] = f2bf(v1[3]);
        *(us8*)(&XsL[r * LDP + k8 * 8]) = o;
      } else {
        const unsigned short* src = (const unsigned short*)Xv + (size_t)(m0 + r) * CC + kk + k8 * 8;
        *(us8*)(&XsL[r * LDP + k8 * 8]) = *(const us8*)src;
      }
    }
#pragma unroll
    for (int i = 0; i < 4; i++) {            // stage W tile 128x64 (bf16)
      int c = tid + 256 * i;
      int r = c >> 3, k8 = c & 7;
      const unsigned short* src = W + (size_t)(n0 + r) * CC + kk + k8 * 8;
      *(us8*)(&WsL[r * LDP + k8 * 8]) = *(const us8*)src;
    }
    __syncthreads();
#pragma unroll
    for (int ks = 0; ks < 2; ks++) {
      us8 a[4], b[4];
#pragma unroll
      for (int m = 0; m < 4; m++)
        a[m] = *(const us8*)(&XsL[(wr * 64 + m * 16 + l16) * LDP + ks * 32 + g * 8]);
#pragma unroll
      for (int n = 0; n < 4; n++)
        b[n] = *(const us8*)(&WsL[(wc * 64 + n * 16 + l16) * LDP + ks * 32 + g * 8]);
#pragma unroll
      for (int m = 0; m < 4; m++)
#pragma unroll
        for (int n = 0; n < 4; n++)
          acc[m][n] = MFMA(a[m], b[n], acc[m][n]);
    }
  }
}

// ---------------------------------------------------------------- QKV projection (grid.z selects q/k/v)
__global__ __launch_bounds__(256) void gemm_qkv(const float* xq, const float* xk, const float* xv,
                                                const float* bq, const float* bk, const float* bv,
                                                char* ws) {
  __shared__ unsigned short XsL[128 * LDP];
  __shared__ unsigned short WsL[128 * LDP];
  const int z = blockIdx.z;
  const float* X    = (z == 0) ? xq : (z == 1) ? xk : xv;
  const float* bias = (z == 0) ? bq : (z == 1) ? bk : bv;
  const unsigned short* W = (const unsigned short*)(ws + (size_t)z * 524288u);
  unsigned short* out = (unsigned short*)(ws + ((z == 0) ? OFF_Q : (z == 1) ? OFF_K : OFF_V));
  const float osc = (z == 0) ? QSCALE : 1.0f;

  const int m0 = blockIdx.x * 128, n0 = blockIdx.y * 128;
  f4 acc[4][4];
  gemm_core<true>(X, W, m0, n0, acc, XsL, WsL);

  const int tid = threadIdx.x, w = tid >> 6, lane = tid & 63, g = lane >> 4, l16 = lane & 15;
  const int wr = w >> 1, wc = w & 1;
#pragma unroll
  for (int n = 0; n < 4; n++) {
    int col = n0 + wc * 64 + n * 16 + l16;
    float bvv = bias[col];
    int h = col >> 6, d = col & 63;
#pragma unroll
    for (int m = 0; m < 4; m++) {
      int rbase = m0 + wr * 64 + m * 16 + 4 * g;
#pragma unroll
      for (int r = 0; r < 4; r++) {
        int row = rbase + r;                 // row = t*8 + b
        int t = row >> 3, b = row & 7;
        float val = (acc[m][n][r] + bvv) * osc;
        out[(size_t)((b * HH + h) * TT + t) * DD + d] = f2bf(val);
      }
    }
  }
}

// ---------------------------------------------------------------- V [B,H,T,D] -> Vt [B,H,D,T]
__global__ __launch_bounds__(256) void transpose_v(char* ws) {
  __shared__ unsigned short Ts[64 * LDP];
  const unsigned short* V = (const unsigned short*)(ws + OFF_V);
  unsigned short* Vt = (unsigned short*)(ws + OFF_VT);
  const int bh = blockIdx.y, t0 = blockIdx.x * 64;
  const int tid = threadIdx.x;
#pragma unroll
  for (int i = 0; i < 2; i++) {
    int c = tid + 256 * i;                   // 0..511
    int r = c >> 3, k8 = c & 7;              // r = t row, k8 = d chunk
    *(us8*)(&Ts[r * LDP + k8 * 8]) =
        *(const us8*)(V + (size_t)(bh * TT + t0 + r) * DD + k8 * 8);
  }
  __syncthreads();
#pragma unroll
  for (int i = 0; i < 2; i++) {
    int c = tid + 256 * i;
    int d = c >> 3, t8 = c & 7;
    us8 o;
#pragma unroll
    for (int j = 0; j < 8; j++) o[j] = Ts[(t8 * 8 + j) * LDP + d];
    *(us8*)(Vt + (size_t)(bh * DD + d) * TT + t0 + t8 * 8) = o;
  }
}

// ---------------------------------------------------------------- attention: 64 q-rows per block, full softmax (no max-sub)
__global__ __launch_bounds__(256) void attn(char* ws) {
  __shared__ unsigned short Ks[64 * 64];      // [kv][d], 16B chunks XOR-swizzled by row&7
  __shared__ unsigned short Vs[64 * 64];      // [d][kv], same swizzle
  __shared__ unsigned short Ps[4][16 * LDP];  // per-wave P relayout buffer
  const unsigned short* Q  = (const unsigned short*)(ws + OFF_Q);
  const unsigned short* K  = (const unsigned short*)(ws + OFF_K);
  const unsigned short* Vt = (const unsigned short*)(ws + OFF_VT);
  unsigned short* Y = (unsigned short*)(ws + OFF_Y);

  const int bh = blockIdx.y, t0 = blockIdx.x * 64;
  const int tid = threadIdx.x, w = tid >> 6, lane = tid & 63, g = lane >> 4, l16 = lane & 15;

  // Q fragments straight from global (A-layout: row = l16, k-contiguous)
  const int qrow = t0 + w * 16 + l16;
  const unsigned short* qp = Q + (size_t)(bh * TT + qrow) * DD;
  us8 aq[2];
  aq[0] = *(const us8*)(qp + g * 8);
  aq[1] = *(const us8*)(qp + 32 + g * 8);

  f4 accy[4];
#pragma unroll
  for (int i = 0; i < 4; i++) accy[i] = (f4){0.f, 0.f, 0.f, 0.f};
  float rowsum[4] = {0.f, 0.f, 0.f, 0.f};

  const unsigned short* Kbh = K + (size_t)bh * TT * DD;
  const unsigned short* Vbh = Vt + (size_t)bh * DD * TT;

  for (int kt = 0; kt < TT; kt += 64) {
    __syncthreads();
#pragma unroll
    for (int i = 0; i < 2; i++) {            // stage K tile [64 kv][64 d]
      int c = tid + 256 * i;
      int r = c >> 3, ch = c & 7;
      us8 v = *(const us8*)(Kbh + (size_t)(kt + r) * DD + ch * 8);
      int chs = ch ^ (r & 7);
      *(us8*)((char*)Ks + r * 128 + chs * 16) = v;
    }
#pragma unroll
    for (int i = 0; i < 2; i++) {            // stage Vt tile [64 d][64 kv]
      int c = tid + 256 * i;
      int r = c >> 3, ch = c & 7;
      us8 v = *(const us8*)(Vbh + (size_t)r * TT + kt + ch * 8);
      int chs = ch ^ (r & 7);
      *(us8*)((char*)Vs + r * 128 + chs * 16) = v;
    }
    __syncthreads();

    // S = Q · K^T   (D rows = q_local 4g+reg, cols = kv l16+16nf)
    f4 s[4];
#pragma unroll
    for (int nf = 0; nf < 4; nf++) {
      s[nf] = (f4){0.f, 0.f, 0.f, 0.f};
#pragma unroll
      for (int ks = 0; ks < 2; ks++) {
        int krow = nf * 16 + l16;
        us8 kb = *(const us8*)((char*)Ks + krow * 128 + (((ks * 4 + g) ^ (krow & 7)) * 16));
        s[nf] = MFMA(aq[ks], kb, s[nf]);
      }
    }

    // P = exp2(S)  (Q carries (1/8)*log2e), accumulate denominator, relay P via LDS
#pragma unroll
    for (int nf = 0; nf < 4; nf++) {
#pragma unroll
      for (int r = 0; r < 4; r++) {
        float p = exp2f(s[nf][r]);
        rowsum[r] += p;
        Ps[w][(4 * g + r) * LDP + l16 + 16 * nf] = f2bf(p);
      }
    }
    asm volatile("" ::: "memory");           // order LDS writes before reads (same wave, DS FIFO does the rest)

    // Y += P · V
    us8 ap[2];
    ap[0] = *(const us8*)(&Ps[w][l16 * LDP + g * 8]);
    ap[1] = *(const us8*)(&Ps[w][l16 * LDP + 32 + g * 8]);
#pragma unroll
    for (int nd = 0; nd < 4; nd++) {
#pragma unroll
      for (int ks = 0; ks < 2; ks++) {
        int drow = nd * 16 + l16;
        us8 vb = *(const us8*)((char*)Vs + drow * 128 + (((ks * 4 + g) ^ (drow & 7)) * 16));
        accy[nd] = MFMA(ap[ks], vb, accy[nd]);
      }
    }
  }

  // finish softmax: reduce denominator across the 16 lanes of each group
#pragma unroll
  for (int r = 0; r < 4; r++) {
    float v = rowsum[r];
    v += __shfl_xor(v, 1); v += __shfl_xor(v, 2);
    v += __shfl_xor(v, 4); v += __shfl_xor(v, 8);
    rowsum[r] = 1.0f / v;
  }

  const int b = bh >> 3, h = bh & 7;
#pragma unroll
  for (int nd = 0; nd < 4; nd++) {
    int d = l16 + 16 * nd;
#pragma unroll
    for (int r = 0; r < 4; r++) {
      int trow = t0 + w * 16 + 4 * g + r;
      Y[(size_t)(b * TT + trow) * CC + h * DD + d] = f2bf(accy[nd][r] * rowsum[r]);
    }
  }
}

// ---------------------------------------------------------------- output projection -> f32 [T,B,C]
__global__ __launch_bounds__(256) void gemm_oproj(char* ws, const float* bo, float* out) {
  __shared__ unsigned short XsL[128 * LDP];
  __shared__ unsigned short WsL[128 * LDP];
  const unsigned short* X = (const unsigned short*)(ws + OFF_Y);   // [B*T][C] bf16, row = b*T+t
  const unsigned short* W = (const unsigned short*)(ws + OFF_WO);
  const int m0 = blockIdx.x * 128, n0 = blockIdx.y * 128;
  f4 acc[4][4];
  gemm_core<false>(X, W, m0, n0, acc, XsL, WsL);

  const int tid = threadIdx.x, w = tid >> 6, lane = tid & 63, g = lane >> 4, l16 = lane & 15;
  const int wr = w >> 1, wc = w & 1;
#pragma unroll
  for (int n = 0; n < 4; n++) {
    int col = n0 + wc * 64 + n * 16 + l16;
    float bvv = bo[col];
#pragma unroll
    for (int m = 0; m < 4; m++) {
      int rbase = m0 + wr * 64 + m * 16 + 4 * g;
#pragma unroll
      for (int r = 0; r < 4; r++) {
        int row = rbase + r;                 // row = b*2048 + t
        int b = row >> 11, t = row & 2047;
        out[(size_t)(t * BB + b) * CC + col] = acc[m][n][r] + bvv;
      }
    }
  }
}

// ---------------------------------------------------------------- launch
extern "C" void kernel_launch(void* const* d_in, const int* in_sizes, int n_in,
                              void* d_out, int out_size, void* d_ws, size_t ws_size,
                              hipStream_t stream) {
  const float* query = (const float*)d_in[0];
  const float* key_  = (const float*)d_in[1];
  const float* value = (const float*)d_in[2];
  const float* Wq = (const float*)d_in[3];
  const float* bq = (const float*)d_in[4];
  const float* Wk = (const float*)d_in[5];
  const float* bk = (const float*)d_in[6];
  const float* Wv = (const float*)d_in[7];
  const float* bv = (const float*)d_in[8];
  const float* Wo = (const float*)d_in[9];
  const float* bo = (const float*)d_in[10];
  char* ws = (char*)d_ws;

  prep_w<<<dim3(256), dim3(256), 0, stream>>>(Wq, Wk, Wv, Wo, (unsigned short*)ws);
  gemm_qkv<<<dim3(128, 4, 3), dim3(256), 0, stream>>>(query, key_, value, bq, bk, bv, ws);
  transpose_v<<<dim3(32, 64), dim3(256), 0, stream>>>(ws);
  attn<<<dim3(32, 64), dim3(256), 0, stream>>>(ws);
  gemm_oproj<<<dim3(128, 4), dim3(256), 0, stream>>>(ws, bo, (float*)d_out);
}

// Round 3
// 294.582 us; speedup vs baseline: 1.2250x; 1.2250x over previous
//
#include <hip/hip_runtime.h>

// ---------------------------------------------------------------- constants
#define TT 2048
#define BB 8
#define CC 512
#define HH 8
#define DD 64
#define MM (TT*BB)          // 16384 GEMM rows
#define LDP 72              // padded LDS leading dim (bf16 elems): 144B stride -> 2-way max conflict
#define QSCALE (0.125f * 1.44269950408889634f)   // (1/sqrt(D)) * log2(e), folded into stored Q

// ws byte offsets
#define OFF_WQ 0u
#define OFF_WK (512u<<10)
#define OFF_WV (1024u<<10)
#define OFF_WO (1536u<<10)
#define OFF_Q  (2u<<20)      // 16 MB  [B,H,T,D] bf16 (pre-scaled by QSCALE)
#define OFF_K  (18u<<20)     // 16 MB  [B,H,T,D] bf16
#define OFF_VT (34u<<20)     // 16 MB  [B,H,D,T] bf16
#define OFF_V  (50u<<20)     // 16 MB  [B,H,T,D] bf16; dead after transpose
#define OFF_Y  OFF_V         // attention output [B,T,C] bf16 reuses V region

typedef __attribute__((ext_vector_type(8)))  unsigned short us8;
typedef __attribute__((ext_vector_type(4)))  unsigned short us4;
typedef __attribute__((ext_vector_type(4)))  float f4;
typedef __attribute__((ext_vector_type(16))) float f16v;
typedef __attribute__((ext_vector_type(4)))  unsigned int u4;
typedef __bf16 bf8v __attribute__((ext_vector_type(8)));

__device__ __forceinline__ unsigned short f2bf(float f) {
  unsigned u = __float_as_uint(f);
  u += 0x7fffu + ((u >> 16) & 1u);          // RNE
  return (unsigned short)(u >> 16);
}

__device__ __forceinline__ f4 MFMA(us8 a, us8 b, f4 c) {
  return __builtin_amdgcn_mfma_f32_16x16x32_bf16(
      __builtin_bit_cast(bf8v, a), __builtin_bit_cast(bf8v, b), c, 0, 0, 0);
}

__device__ __forceinline__ f16v MFMA32(us8 a, us8 b, f16v c) {
  return __builtin_amdgcn_mfma_f32_32x32x16_bf16(
      __builtin_bit_cast(bf8v, a), __builtin_bit_cast(bf8v, b), c, 0, 0, 0);
}

__device__ __forceinline__ unsigned cvt_pk_bf16(float lo, float hi) {
  unsigned r;
  asm("v_cvt_pk_bf16_f32 %0, %1, %2" : "=v"(r) : "v"(lo), "v"(hi));
  return r;
}

// ---------------------------------------------------------------- prep: weights f32 -> bf16
__global__ __launch_bounds__(256) void prep_w(const float* wq, const float* wk,
                                              const float* wv, const float* wo,
                                              unsigned short* dst) {
  int i = blockIdx.x * 256 + threadIdx.x;   // 0..65535, one float4 per matrix
  const float* srcs[4] = {wq, wk, wv, wo};
#pragma unroll
  for (int m = 0; m < 4; m++) {
    f4 v = ((const f4*)srcs[m])[i];
    us4 o;
    o[0] = f2bf(v[0]); o[1] = f2bf(v[1]); o[2] = f2bf(v[2]); o[3] = f2bf(v[3]);
    ((us4*)(dst + m * 262144))[i] = o;
  }
}

// ---------------------------------------------------------------- GEMM core: C[128,128] tile of X[M,512] @ Wb[512,512]^T
template <bool XF32>
__device__ __forceinline__ void gemm_core(const void* Xv, const unsigned short* W,
                                          int m0, int n0, f4 acc[4][4],
                                          unsigned short* XsL, unsigned short* WsL) {
  const int tid = threadIdx.x;
  const int w = tid >> 6, lane = tid & 63, g = lane >> 4, l16 = lane & 15;
  const int wr = w >> 1, wc = w & 1;
#pragma unroll
  for (int m = 0; m < 4; m++)
#pragma unroll
    for (int n = 0; n < 4; n++) acc[m][n] = (f4){0.f, 0.f, 0.f, 0.f};

  for (int kk = 0; kk < CC; kk += 64) {
    __syncthreads();
#pragma unroll
    for (int i = 0; i < 4; i++) {            // stage X tile 128x64
      int c = tid + 256 * i;
      int r = c >> 3, k8 = c & 7;
      if (XF32) {
        const float* src = (const float*)Xv + (size_t)(m0 + r) * CC + kk + k8 * 8;
        f4 v0 = ((const f4*)src)[0];
        f4 v1 = ((const f4*)src)[1];
        us8 o;
        o[0] = f2bf(v0[0]); o[1] = f2bf(v0[1]); o[2] = f2bf(v0[2]); o[3] = f2bf(v0[3]);
        o[4] = f2bf(v1[0]); o[5] = f2bf(v1[1]); o[6] = f2bf(v1[2]); o[7] = f2bf(v1[3]);
        *(us8*)(&XsL[r * LDP + k8 * 8]) = o;
      } else {
        const unsigned short* src = (const unsigned short*)Xv + (size_t)(m0 + r) * CC + kk + k8 * 8;
        *(us8*)(&XsL[r * LDP + k8 * 8]) = *(const us8*)src;
      }
    }
#pragma unroll
    for (int i = 0; i < 4; i++) {            // stage W tile 128x64 (bf16)
      int c = tid + 256 * i;
      int r = c >> 3, k8 = c & 7;
      const unsigned short* src = W + (size_t)(n0 + r) * CC + kk + k8 * 8;
      *(us8*)(&WsL[r * LDP + k8 * 8]) = *(const us8*)src;
    }
    __syncthreads();
#pragma unroll
    for (int ks = 0; ks < 2; ks++) {
      us8 a[4], b[4];
#pragma unroll
      for (int m = 0; m < 4; m++)
        a[m] = *(const us8*)(&XsL[(wr * 64 + m * 16 + l16) * LDP + ks * 32 + g * 8]);
#pragma unroll
      for (int n = 0; n < 4; n++)
        b[n] = *(const us8*)(&WsL[(wc * 64 + n * 16 + l16) * LDP + ks * 32 + g * 8]);
#pragma unroll
      for (int m = 0; m < 4; m++)
#pragma unroll
        for (int n = 0; n < 4; n++)
          acc[m][n] = MFMA(a[m], b[n], acc[m][n]);
    }
  }
}

// ---------------------------------------------------------------- QKV projection (grid.z selects q/k/v)
__global__ __launch_bounds__(256) void gemm_qkv(const float* xq, const float* xk, const float* xv,
                                                const float* bq, const float* bk, const float* bv,
                                                char* ws) {
  __shared__ unsigned short XsL[128 * LDP];
  __shared__ unsigned short WsL[128 * LDP];
  const int z = blockIdx.z;
  const float* X    = (z == 0) ? xq : (z == 1) ? xk : xv;
  const float* bias = (z == 0) ? bq : (z == 1) ? bk : bv;
  const unsigned short* W = (const unsigned short*)(ws + (size_t)z * 524288u);
  unsigned short* out = (unsigned short*)(ws + ((z == 0) ? OFF_Q : (z == 1) ? OFF_K : OFF_V));
  const float osc = (z == 0) ? QSCALE : 1.0f;

  const int m0 = blockIdx.x * 128, n0 = blockIdx.y * 128;
  f4 acc[4][4];
  gemm_core<true>(X, W, m0, n0, acc, XsL, WsL);

  const int tid = threadIdx.x, w = tid >> 6, lane = tid & 63, g = lane >> 4, l16 = lane & 15;
  const int wr = w >> 1, wc = w & 1;
#pragma unroll
  for (int n = 0; n < 4; n++) {
    int col = n0 + wc * 64 + n * 16 + l16;
    float bvv = bias[col];
    int h = col >> 6, d = col & 63;
#pragma unroll
    for (int m = 0; m < 4; m++) {
      int rbase = m0 + wr * 64 + m * 16 + 4 * g;
#pragma unroll
      for (int r = 0; r < 4; r++) {
        int row = rbase + r;                 // row = t*8 + b
        int t = row >> 3, b = row & 7;
        float val = (acc[m][n][r] + bvv) * osc;
        out[(size_t)((b * HH + h) * TT + t) * DD + d] = f2bf(val);
      }
    }
  }
}

// ---------------------------------------------------------------- V [B,H,T,D] -> Vt [B,H,D,T]
__global__ __launch_bounds__(256) void transpose_v(char* ws) {
  __shared__ unsigned short Ts[64 * LDP];
  const unsigned short* V = (const unsigned short*)(ws + OFF_V);
  unsigned short* Vt = (unsigned short*)(ws + OFF_VT);
  const int bh = blockIdx.y, t0 = blockIdx.x * 64;
  const int tid = threadIdx.x;
#pragma unroll
  for (int i = 0; i < 2; i++) {
    int c = tid + 256 * i;
    int r = c >> 3, k8 = c & 7;
    *(us8*)(&Ts[r * LDP + k8 * 8]) =
        *(const us8*)(V + (size_t)(bh * TT + t0 + r) * DD + k8 * 8);
  }
  __syncthreads();
#pragma unroll
  for (int i = 0; i < 2; i++) {
    int c = tid + 256 * i;
    int d = c >> 3, t8 = c & 7;
    us8 o;
#pragma unroll
    for (int j = 0; j < 8; j++) o[j] = Ts[(t8 * 8 + j) * LDP + d];
    *(us8*)(Vt + (size_t)(bh * DD + d) * TT + t0 + t8 * 8) = o;
  }
}

// ---------------------------------------------------------------- attention v3: 8 waves x 32 q-rows, 32x32x16 MFMA,
// swapped QK^T (S^T = K.Q^T), P stays in registers; relay to PV A-frags via cvt_pk + shfl_xor(32)
// (deterministic semantics; permlane32_swap return-word order was the round-2 failure suspect).
__global__ __launch_bounds__(512) void attn(char* ws) {
  __shared__ unsigned short Ks[64 * 64];      // [kv][d], 16B chunks XOR-swizzled by row&7
  __shared__ unsigned short Vs[64 * 64];      // [d][kv], same swizzle
  __shared__ float Rs[8 * 32];                // per-wave 1/rowsum broadcast
  const unsigned short* Q  = (const unsigned short*)(ws + OFF_Q);
  const unsigned short* K  = (const unsigned short*)(ws + OFF_K);
  const unsigned short* Vt = (const unsigned short*)(ws + OFF_VT);
  unsigned short* Y = (unsigned short*)(ws + OFF_Y);

  const int bh = blockIdx.y, t0 = blockIdx.x * 256;
  const int tid = threadIdx.x, w = tid >> 6, lane = tid & 63;
  const int l31 = lane & 31, h = lane >> 5;
  const int swz = l31 & 7;

  const unsigned short* Kbh = K + (size_t)bh * TT * DD;
  const unsigned short* Vbh = Vt + (size_t)bh * DD * TT;

  // Q B-fragments (B[k][q] = Q[q][k]): lane(col=q=l31, h) holds k = ks*16 + h*8 + j
  const int qrow = t0 + w * 32 + l31;
  const unsigned short* qp = Q + ((size_t)bh * TT + qrow) * DD + h * 8;
  us8 qf[4];
#pragma unroll
  for (int ks = 0; ks < 4; ks++) qf[ks] = *(const us8*)(qp + ks * 16);

  f16v accy[2];
#pragma unroll
  for (int i = 0; i < 16; i++) { accy[0][i] = 0.f; accy[1][i] = 0.f; }
  float rsum = 0.f;

  // staging: 512 threads cover 64 rows x 8 chunks of 16B
  const int sr = tid >> 3, sch = tid & 7, schs = sch ^ (sr & 7);
  const unsigned short* Kg = Kbh + (size_t)sr * DD + sch * 8;
  const unsigned short* Vg = Vbh + (size_t)sr * TT + sch * 8;
  char* kdst = (char*)Ks + sr * 128 + schs * 16;
  char* vdst = (char*)Vs + sr * 128 + schs * 16;

  for (int kt = 0; kt < TT; kt += 64) {
    __syncthreads();
    *(us8*)kdst = *(const us8*)(Kg + (size_t)kt * DD);
    *(us8*)vdst = *(const us8*)(Vg + kt);
    __syncthreads();

#pragma unroll
    for (int f = 0; f < 2; f++) {           // kv 32-row halves
      // S^T[kv][q] = K . Q^T
      f16v s;
#pragma unroll
      for (int i = 0; i < 16; i++) s[i] = 0.f;
#pragma unroll
      for (int ks = 0; ks < 4; ks++) {
        us8 kf = *(const us8*)((char*)Ks + (f * 32 + l31) * 128 + (((ks * 2 + h) ^ swz) * 16));
        s = MFMA32(kf, qf[ks], s);
      }
      // P = exp2(S); lane(q=l31,h) reg r16 holds kv32 = 8*(r16>>2) + 4h + (r16&3)
      float p[16];
#pragma unroll
      for (int r = 0; r < 16; r++) {
        p[r] = __builtin_amdgcn_exp2f(s[r]);
        rsum += p[r];
      }
      unsigned dc0[4], dc1[4];
#pragma unroll
      for (int q2 = 0; q2 < 4; q2++) {
        dc0[q2] = cvt_pk_bf16(p[4 * q2 + 0], p[4 * q2 + 1]);   // kv32 = 8q2+4h+{0,1}
        dc1[q2] = cvt_pk_bf16(p[4 * q2 + 2], p[4 * q2 + 3]);   // kv32 = 8q2+4h+{2,3}
      }
      // PV A-frag for kss: lane(q,h) word w2/hf needs kv32 = kss*16 + 8h + 2*w2 + hf.
      // Half-exchange via shfl_xor(32): source lane pre-selects what the PARTNER needs.
#pragma unroll
      for (int kss = 0; kss < 2; kss++) {
        int ks = f * 2 + kss;
        unsigned z0 = h ? dc0[2 * kss + 1] : dc0[2 * kss];   // own-needed word
        unsigned y0 = h ? dc0[2 * kss]     : dc0[2 * kss + 1]; // partner-needed word
        unsigned z1 = h ? dc1[2 * kss + 1] : dc1[2 * kss];
        unsigned y1 = h ? dc1[2 * kss]     : dc1[2 * kss + 1];
        unsigned s0 = __shfl_xor(y0, 32);
        unsigned s1 = __shfl_xor(y1, 32);
        unsigned w0 = h ? s0 : z0;   // kv32 = kss*16+8h+{0,1}
        unsigned w1 = h ? s1 : z1;   // {2,3}
        unsigned w2 = h ? z0 : s0;   // {4,5}
        unsigned w3 = h ? z1 : s1;   // {6,7}
        u4 av = (u4){w0, w1, w2, w3};
        us8 af = __builtin_bit_cast(us8, av);
#pragma unroll
        for (int nd = 0; nd < 2; nd++) {
          us8 vb = *(const us8*)((char*)Vs + (nd * 32 + l31) * 128 + (((ks * 2 + h) ^ swz) * 16));
          accy[nd] = MFMA32(af, vb, accy[nd]);
        }
      }
    }
  }

  // finish softmax: combine the two lane-halves' partial sums (kv coverage is complementary)
  rsum += __shfl_xor(rsum, 32);
  float inv = 1.0f / rsum;
  if (h == 0) Rs[w * 32 + l31] = inv;
  __syncthreads();

  const int b = bh >> 3, hh = bh & 7;
#pragma unroll
  for (int nd = 0; nd < 2; nd++) {
    int d = nd * 32 + l31;
#pragma unroll
    for (int r = 0; r < 16; r++) {
      int q = 8 * (r >> 2) + 4 * h + (r & 3);
      int trow = t0 + w * 32 + q;
      float v = accy[nd][r] * Rs[w * 32 + q];
      Y[(size_t)(b * TT + trow) * CC + hh * DD + d] = f2bf(v);
    }
  }
}

// ---------------------------------------------------------------- output projection -> f32 [T,B,C]
__global__ __launch_bounds__(256) void gemm_oproj(char* ws, const float* bo, float* out) {
  __shared__ unsigned short XsL[128 * LDP];
  __shared__ unsigned short WsL[128 * LDP];
  const unsigned short* X = (const unsigned short*)(ws + OFF_Y);   // [B*T][C] bf16
  const unsigned short* W = (const unsigned short*)(ws + OFF_WO);
  const int m0 = blockIdx.x * 128, n0 = blockIdx.y * 128;
  f4 acc[4][4];
  gemm_core<false>(X, W, m0, n0, acc, XsL, WsL);

  const int tid = threadIdx.x, w = tid >> 6, lane = tid & 63, g = lane >> 4, l16 = lane & 15;
  const int wr = w >> 1, wc = w & 1;
#pragma unroll
  for (int n = 0; n < 4; n++) {
    int col = n0 + wc * 64 + n * 16 + l16;
    float bvv = bo[col];
#pragma unroll
    for (int m = 0; m < 4; m++) {
      int rbase = m0 + wr * 64 + m * 16 + 4 * g;
#pragma unroll
      for (int r = 0; r < 4; r++) {
        int row = rbase + r;                 // row = b*2048 + t
        int b = row >> 11, t = row & 2047;
        out[(size_t)(t * BB + b) * CC + col] = acc[m][n][r] + bvv;
      }
    }
  }
}

// ---------------------------------------------------------------- launch
extern "C" void kernel_launch(void* const* d_in, const int* in_sizes, int n_in,
                              void* d_out, int out_size, void* d_ws, size_t ws_size,
                              hipStream_t stream) {
  const float* query = (const float*)d_in[0];
  const float* key_  = (const float*)d_in[1];
  const float* value = (const float*)d_in[2];
  const float* Wq = (const float*)d_in[3];
  const float* bq = (const float*)d_in[4];
  const float* Wk = (const float*)d_in[5];
  const float* bk = (const float*)d_in[6];
  const float* Wv = (const float*)d_in[7];
  const float* bv = (const float*)d_in[8];
  const float* Wo = (const float*)d_in[9];
  const float* bo = (const float*)d_in[10];
  char* ws = (char*)d_ws;

  prep_w<<<dim3(256), dim3(256), 0, stream>>>(Wq, Wk, Wv, Wo, (unsigned short*)ws);
  gemm_qkv<<<dim3(128, 4, 3), dim3(256), 0, stream>>>(query, key_, value, bq, bk, bv, ws);
  transpose_v<<<dim3(32, 64), dim3(256), 0, stream>>>(ws);
  attn<<<dim3(8, 64), dim3(512), 0, stream>>>(ws);
  gemm_oproj<<<dim3(128, 4), dim3(256), 0, stream>>>(ws, bo, (float*)d_out);
}